// Round 2
// baseline (733.599 us; speedup 1.0000x reference)
//
#include <hip/hip_runtime.h>

#define NUM_CODES 1296
#define DDIM 64
#define KT 108            // codes per LDS tile; 1296 = 12*108, no tail
#define NTILES 12
#define THREADS 256
#define NUM_Q 131072      // 32*64*64

// Embedding norms ||e||^2, emulating numpy's pairwise (8-accumulator) sum
// with contraction off (square rounded, then added) to track the np reference.
__global__ void vq_enorm(const float* __restrict__ emb, float* __restrict__ norms) {
    int k = blockIdx.x * blockDim.x + threadIdx.x;
    if (k >= NUM_CODES) return;
    const float* e = emb + (size_t)k * DDIM;
    {
#pragma clang fp contract(off)
        float r[8];
#pragma unroll
        for (int j = 0; j < 8; ++j) { float t = e[j] * e[j]; r[j] = t; }
#pragma unroll
        for (int i = 1; i < 8; ++i) {
#pragma unroll
            for (int j = 0; j < 8; ++j) { float t = e[i*8+j] * e[i*8+j]; r[j] += t; }
        }
        norms[k] = ((r[0]+r[1])+(r[2]+r[3])) + ((r[4]+r[5])+(r[6]+r[7]));
    }
}

__global__ __launch_bounds__(THREADS) void vq_main(const float* __restrict__ x,
                                                   const float* __restrict__ emb,
                                                   const float* __restrict__ norms,
                                                   float* __restrict__ out) {
    __shared__ float se[KT * DDIM];   // 27648 B
    __shared__ float sn[KT];
    const int q = blockIdx.x * THREADS + threadIdx.x;

    // Load this thread's query vector into registers (16 x dwordx4).
    float xr[DDIM];
    {
        const float4* xp = (const float4*)(x + (size_t)q * DDIM);
#pragma unroll
        for (int i = 0; i < DDIM/4; ++i) {
            float4 v = xp[i];
            xr[4*i+0] = v.x; xr[4*i+1] = v.y; xr[4*i+2] = v.z; xr[4*i+3] = v.w;
        }
    }

    // ||x||^2 — per-query constant; its rounding shifts all distances equally,
    // so argmin is invariant to summation order. Use numpy-style anyway.
    float x1;
    {
#pragma clang fp contract(off)
        float r[8];
#pragma unroll
        for (int j = 0; j < 8; ++j) { float t = xr[j]*xr[j]; r[j] = t; }
#pragma unroll
        for (int i = 1; i < 8; ++i) {
#pragma unroll
            for (int j = 0; j < 8; ++j) { float t = xr[i*8+j]*xr[i*8+j]; r[j] += t; }
        }
        x1 = ((r[0]+r[1])+(r[2]+r[3])) + ((r[4]+r[5])+(r[6]+r[7]));
    }

    float best = __builtin_inff();
    int bestk = 0;

    for (int t = 0; t < NTILES; ++t) {
        __syncthreads();   // previous tile fully consumed before overwrite
        {
            const float4* ep = (const float4*)(emb + (size_t)t * KT * DDIM);
            float4* sp = (float4*)se;
            for (int i = threadIdx.x; i < (KT*DDIM)/4; i += THREADS) sp[i] = ep[i];
            if (threadIdx.x < KT) sn[threadIdx.x] = norms[t*KT + threadIdx.x];
        }
        __syncthreads();

#pragma unroll 2
        for (int kk = 0; kk < KT; ++kk) {
            const float* e = se + kk*DDIM;   // same addr across wave -> LDS broadcast
            float dot = 0.f;
#pragma unroll
            for (int d = 0; d < DDIM; ++d) dot = fmaf(xr[d], e[d], dot);
            // Reference rounding: (x1 + x2) - 2*x3. 2*dot is exact, the
            // subtract rounds once (fma-contraction gives identical bits).
            float dist = (x1 + sn[kk]) - 2.0f*dot;
            int kg = t*KT + kk;
            if (dist < best) { best = dist; bestk = kg; }   // strict < == first-index tiebreak
        }
    }

    // Output 0: codes as float values (harness reads non-bf16 d_out as float32)
    out[q] = (float)bestk;
    // Output 1: gathered embedding row
    float4* op = (float4*)(out + (size_t)NUM_Q + (size_t)q * DDIM);
    const float4* bp = (const float4*)(emb + (size_t)bestk * DDIM);
#pragma unroll
    for (int i = 0; i < DDIM/4; ++i) op[i] = bp[i];
}

extern "C" void kernel_launch(void* const* d_in, const int* in_sizes, int n_in,
                              void* d_out, int out_size, void* d_ws, size_t ws_size,
                              hipStream_t stream) {
    const float* x   = (const float*)d_in[0];
    const float* emb = (const float*)d_in[1];
    float* norms = (float*)d_ws;   // 1296 floats of scratch

    hipLaunchKernelGGL(vq_enorm, dim3((NUM_CODES + 255) / 256), dim3(256), 0, stream,
                       emb, norms);
    hipLaunchKernelGGL(vq_main, dim3(NUM_Q / THREADS), dim3(THREADS), 0, stream,
                       x, emb, norms, (float*)d_out);
}

// Round 3
// 380.280 us; speedup vs baseline: 1.9291x; 1.9291x over previous
//
#include <hip/hip_runtime.h>

#define NUM_CODES 1296
#define DDIM 64
#define NUM_Q 131072      // 32*64*64
#define BM 128            // queries per block; 131072 = 1024 * 128 exactly
#define BN 192            // codes per N-tile; 7 tiles cover 1296 (last masked)
#define TM 16             // queries per thread
#define TN 12             // codes per thread
#define KC 32             // k-chunk staged in LDS for embeddings
#define SXLD 132          // sx row pitch (128 + 4): float4-aligned, conflict-free frags
#define SELD 196          // se row pitch (192 + 4)
#define NTILE 7
#define THREADS 128       // 8 ty * 16 tx

// Embedding norms ||e||^2, numpy pairwise (8-accumulator) order, contraction off.
__global__ void vq_enorm(const float* __restrict__ emb, float* __restrict__ norms) {
    int k = blockIdx.x * blockDim.x + threadIdx.x;
    if (k >= NUM_CODES) return;
    const float* e = emb + (size_t)k * DDIM;
    {
#pragma clang fp contract(off)
        float r[8];
#pragma unroll
        for (int j = 0; j < 8; ++j) { float t = e[j] * e[j]; r[j] = t; }
#pragma unroll
        for (int i = 1; i < 8; ++i) {
#pragma unroll
            for (int j = 0; j < 8; ++j) { float t = e[i*8+j] * e[i*8+j]; r[j] += t; }
        }
        norms[k] = ((r[0]+r[1])+(r[2]+r[3])) + ((r[4]+r[5])+(r[6]+r[7]));
    }
}

__global__ __launch_bounds__(THREADS, 1) void vq_main(
        const float* __restrict__ x, const float* __restrict__ emb,
        const float* __restrict__ norms, float* __restrict__ out) {
    __shared__ float sx[DDIM * SXLD];   // 33792 B, x tile k-major, full K
    __shared__ float se[KC * SELD];     // 25088 B, e chunk k-major
    __shared__ float sn[BN];
    __shared__ float x1s[BM];

    const int tid = threadIdx.x;
    const int tx = tid & 15;            // code group
    const int ty = tid >> 4;            // query group (0..7)
    const long qbase = (long)blockIdx.x * BM;

    // ---- stage x tile transposed: sx[d][r] = x[qbase+r][d] ----
    // 128 rows * 16 float4 = 2048 loads / 128 threads = 16 each, coalesced.
#pragma unroll
    for (int u = 0; u < 16; ++u) {
        int idx = u * THREADS + tid;
        int r = idx >> 4, j = idx & 15;
        float4 v = *(const float4*)(x + (qbase + r) * DDIM + j * 4);
        sx[(4*j+0)*SXLD + r] = v.x;
        sx[(4*j+1)*SXLD + r] = v.y;
        sx[(4*j+2)*SXLD + r] = v.z;
        sx[(4*j+3)*SXLD + r] = v.w;
    }
    __syncthreads();

    // ---- ||x||^2 per query, numpy pairwise order (element order d=0..63) ----
    {
#pragma clang fp contract(off)
        float r8[8];
#pragma unroll
        for (int j = 0; j < 8; ++j) { float v = sx[j*SXLD + tid]; float t = v*v; r8[j] = t; }
#pragma unroll
        for (int i = 1; i < 8; ++i) {
#pragma unroll
            for (int j = 0; j < 8; ++j) { float v = sx[(i*8+j)*SXLD + tid]; float t = v*v; r8[j] += t; }
        }
        x1s[tid] = ((r8[0]+r8[1])+(r8[2]+r8[3])) + ((r8[4]+r8[5])+(r8[6]+r8[7]));
    }
    // x1s is read only in the epilogue, after at least one __syncthreads().

    float best[TM]; int bestk[TM];
#pragma unroll
    for (int i = 0; i < TM; ++i) { best[i] = __builtin_inff(); bestk[i] = 0; }

    for (int t = 0; t < NTILE; ++t) {
        const int tb = t * BN;
        float acc[TM][TN];
#pragma unroll
        for (int i = 0; i < TM; ++i)
#pragma unroll
            for (int j = 0; j < TN; ++j) acc[i][j] = 0.f;

        for (int kc = 0; kc < DDIM / KC; ++kc) {
            __syncthreads();   // previous chunk fully consumed
            // stage se[k][c] = emb[clamp(tb+c)][kc*KC + k]; 1536 float4 / 128 thr
#pragma unroll
            for (int u = 0; u < 12; ++u) {
                int idx = u * THREADS + tid;
                int c = idx >> 3, j = idx & 7;
                int cg = tb + c; if (cg > NUM_CODES - 1) cg = NUM_CODES - 1;
                float4 v = *(const float4*)(emb + (long)cg * DDIM + kc * KC + j * 4);
                se[(4*j+0)*SELD + c] = v.x;
                se[(4*j+1)*SELD + c] = v.y;
                se[(4*j+2)*SELD + c] = v.z;
                se[(4*j+3)*SELD + c] = v.w;
            }
            if (kc == 0) {
                for (int c = tid; c < BN; c += THREADS)
                    sn[c] = (tb + c < NUM_CODES) ? norms[tb + c] : __builtin_inff();
            }
            __syncthreads();

#pragma unroll 2
            for (int k = 0; k < KC; ++k) {
                const float* ap = sx + (kc*KC + k)*SXLD + ty*TM;
                const float* bp = se + k*SELD + tx*TN;
                float av[TM], bv[TN];
#pragma unroll
                for (int p = 0; p < TM/4; ++p) {
                    float4 v = *(const float4*)(ap + 4*p);
                    av[4*p+0]=v.x; av[4*p+1]=v.y; av[4*p+2]=v.z; av[4*p+3]=v.w;
                }
#pragma unroll
                for (int p = 0; p < TN/4; ++p) {
                    float4 v = *(const float4*)(bp + 4*p);
                    bv[4*p+0]=v.x; bv[4*p+1]=v.y; bv[4*p+2]=v.z; bv[4*p+3]=v.w;
                }
#pragma unroll
                for (int i = 0; i < TM; ++i)
#pragma unroll
                    for (int j = 0; j < TN; ++j)
                        acc[i][j] = fmaf(av[i], bv[j], acc[i][j]);  // k ascending: same order as ref kernel
            }
        }

        // ---- argmin update for this tile (codes ascending within thread) ----
#pragma unroll
        for (int i = 0; i < TM; ++i) {
            float x1 = x1s[ty*TM + i];
#pragma unroll
            for (int j = 0; j < TN; ++j) {
                float dist = (x1 + sn[tx*TN + j]) - 2.0f * acc[i][j];
                int kg = tb + tx*TN + j;
                if (dist < best[i]) { best[i] = dist; bestk[i] = kg; }
            }
        }
    }

    // ---- reduce (dist, idx) lexicographically across the 16 tx lanes ----
#pragma unroll
    for (int i = 0; i < TM; ++i) {
        float b = best[i]; int kk = bestk[i];
#pragma unroll
        for (int m = 1; m < 16; m <<= 1) {
            float ob = __shfl_xor(b, m, 64);
            int  ok = __shfl_xor(kk, m, 64);
            if (ob < b || (ob == b && ok < kk)) { b = ob; kk = ok; }
        }
        long q = qbase + ty*TM + i;
        if (tx == 0) out[q] = (float)kk;   // codes as float values
        // 16 lanes gather the 64-float embedding row cooperatively (256 B/instr)
        *(float4*)(out + (long)NUM_Q + q*DDIM + tx*4) =
            *(const float4*)(emb + (long)kk*DDIM + tx*4);
    }
}

extern "C" void kernel_launch(void* const* d_in, const int* in_sizes, int n_in,
                              void* d_out, int out_size, void* d_ws, size_t ws_size,
                              hipStream_t stream) {
    const float* x   = (const float*)d_in[0];
    const float* emb = (const float*)d_in[1];
    float* norms = (float*)d_ws;   // 1296 floats of scratch

    hipLaunchKernelGGL(vq_enorm, dim3((NUM_CODES + 255) / 256), dim3(256), 0, stream,
                       emb, norms);
    hipLaunchKernelGGL(vq_main, dim3(NUM_Q / BM), dim3(THREADS), 0, stream,
                       x, emb, norms, (float*)d_out);
}

// Round 4
// 297.919 us; speedup vs baseline: 2.4624x; 1.2765x over previous
//
#include <hip/hip_runtime.h>

#define NUM_CODES 1296
#define DDIM 64
#define NUM_Q 131072      // 32*64*64
#define BM 128            // queries per block; 131072 = 1024 * 128 exactly
#define BN 192            // codes per N-tile; 7 tiles cover 1296 (last masked)
#define TM 8              // queries per thread
#define TN 12             // codes per thread
#define KC 32             // k-chunk staged in LDS for embeddings
#define SXLD 140          // sx pitch: 140%32=12 (odd*4) -> 2-way staging writes, 16B-aligned rows
#define SELD 196          // se pitch (192 + 4)
#define NTILE 7
#define THREADS 256       // 16 ty * 16 tx

// Embedding norms ||e||^2, numpy pairwise (8-accumulator) order, contraction off.
__global__ void vq_enorm(const float* __restrict__ emb, float* __restrict__ norms) {
    int k = blockIdx.x * blockDim.x + threadIdx.x;
    if (k >= NUM_CODES) return;
    const float* e = emb + (size_t)k * DDIM;
    {
#pragma clang fp contract(off)
        float r[8];
#pragma unroll
        for (int j = 0; j < 8; ++j) { float t = e[j] * e[j]; r[j] = t; }
#pragma unroll
        for (int i = 1; i < 8; ++i) {
#pragma unroll
            for (int j = 0; j < 8; ++j) { float t = e[i*8+j] * e[i*8+j]; r[j] += t; }
        }
        norms[k] = ((r[0]+r[1])+(r[2]+r[3])) + ((r[4]+r[5])+(r[6]+r[7]));
    }
}

__global__ __launch_bounds__(THREADS, 2) void vq_main(
        const float* __restrict__ x, const float* __restrict__ emb,
        const float* __restrict__ norms, float* __restrict__ out) {
    __shared__ float sx[DDIM * SXLD];   // 35840 B, x tile k-major
    __shared__ float se[KC * SELD];     // 25088 B, e chunk k-major
    __shared__ float sn[BN];
    __shared__ float x1s[BM];

    const int tid = threadIdx.x;
    const int tx = tid & 15;            // code group
    const int ty = tid >> 4;            // query group (0..15)
    const long qbase = (long)blockIdx.x * BM;

    // ---- stage x tile transposed: sx[d][r] = x[qbase+r][d] ----
    // 2048 float4 / 256 threads = 8 each, coalesced global reads.
#pragma unroll
    for (int u = 0; u < 8; ++u) {
        int idx = u * THREADS + tid;
        int r = idx >> 4, j = idx & 15;
        float4 v = *(const float4*)(x + (qbase + r) * DDIM + j * 4);
        sx[(4*j+0)*SXLD + r] = v.x;
        sx[(4*j+1)*SXLD + r] = v.y;
        sx[(4*j+2)*SXLD + r] = v.z;
        sx[(4*j+3)*SXLD + r] = v.w;
    }
    __syncthreads();

    // ---- ||x||^2 per query, numpy pairwise order (element order d=0..63) ----
    if (tid < BM) {
#pragma clang fp contract(off)
        float r8[8];
#pragma unroll
        for (int j = 0; j < 8; ++j) { float v = sx[j*SXLD + tid]; float t = v*v; r8[j] = t; }
#pragma unroll
        for (int i = 1; i < 8; ++i) {
#pragma unroll
            for (int j = 0; j < 8; ++j) { float v = sx[(i*8+j)*SXLD + tid]; float t = v*v; r8[j] += t; }
        }
        x1s[tid] = ((r8[0]+r8[1])+(r8[2]+r8[3])) + ((r8[4]+r8[5])+(r8[6]+r8[7]));
    }
    // x1s written once; first read is after the next __syncthreads().

    float best[TM]; int bestk[TM];
#pragma unroll
    for (int i = 0; i < TM; ++i) { best[i] = __builtin_inff(); bestk[i] = 0; }

    for (int t = 0; t < NTILE; ++t) {
        const int tb = t * BN;
        float acc[TM][TN];
#pragma unroll
        for (int i = 0; i < TM; ++i)
#pragma unroll
            for (int j = 0; j < TN; ++j) acc[i][j] = 0.f;

        for (int kc = 0; kc < DDIM / KC; ++kc) {
            __syncthreads();   // previous chunk fully consumed
            // stage se[k][c] = emb[clamp(tb+c)][kc*KC + k]; 1536 float4 / 256 thr
#pragma unroll
            for (int u = 0; u < 6; ++u) {
                int idx = u * THREADS + tid;
                int c = idx >> 3, j = idx & 7;
                int cg = tb + c; if (cg > NUM_CODES - 1) cg = NUM_CODES - 1;
                float4 v = *(const float4*)(emb + (long)cg * DDIM + kc * KC + j * 4);
                se[(4*j+0)*SELD + c] = v.x;
                se[(4*j+1)*SELD + c] = v.y;
                se[(4*j+2)*SELD + c] = v.z;
                se[(4*j+3)*SELD + c] = v.w;
            }
            if (kc == 0) {
                for (int c = tid; c < BN; c += THREADS)
                    sn[c] = (tb + c < NUM_CODES) ? norms[tb + c] : __builtin_inff();
            }
            __syncthreads();

#pragma unroll 2
            for (int k = 0; k < KC; ++k) {
                const float* ap = sx + (kc*KC + k)*SXLD + ty*TM;
                const float* bp = se + k*SELD + tx*TN;
                float av[TM], bv[TN];
#pragma unroll
                for (int p = 0; p < TM/4; ++p) {
                    float4 v = *(const float4*)(ap + 4*p);
                    av[4*p+0]=v.x; av[4*p+1]=v.y; av[4*p+2]=v.z; av[4*p+3]=v.w;
                }
#pragma unroll
                for (int p = 0; p < TN/4; ++p) {
                    float4 v = *(const float4*)(bp + 4*p);
                    bv[4*p+0]=v.x; bv[4*p+1]=v.y; bv[4*p+2]=v.z; bv[4*p+3]=v.w;
                }
#pragma unroll
                for (int i = 0; i < TM; ++i)
#pragma unroll
                    for (int j = 0; j < TN; ++j)
                        acc[i][j] = fmaf(av[i], bv[j], acc[i][j]);  // k ascending: same order as ref
            }
        }

        // ---- argmin update for this tile (codes ascending within thread) ----
#pragma unroll
        for (int i = 0; i < TM; ++i) {
            float x1 = x1s[ty*TM + i];
#pragma unroll
            for (int j = 0; j < TN; ++j) {
                float dist = (x1 + sn[tx*TN + j]) - 2.0f * acc[i][j];
                int kg = tb + tx*TN + j;
                if (dist < best[i]) { best[i] = dist; bestk[i] = kg; }
            }
        }
    }

    // ---- reduce (dist, idx) lexicographically across the 16 tx lanes ----
#pragma unroll
    for (int i = 0; i < TM; ++i) {
        float b = best[i]; int kk = bestk[i];
#pragma unroll
        for (int m = 1; m < 16; m <<= 1) {
            float ob = __shfl_xor(b, m, 64);
            int  ok = __shfl_xor(kk, m, 64);
            if (ob < b || (ob == b && ok < kk)) { b = ob; kk = ok; }
        }
        long q = qbase + ty*TM + i;
        if (tx == 0) out[q] = (float)kk;   // codes as float values
        // 16 lanes gather the 64-float embedding row cooperatively
        *(float4*)(out + (long)NUM_Q + q*DDIM + tx*4) =
            *(const float4*)(emb + (long)kk*DDIM + tx*4);
    }
}

extern "C" void kernel_launch(void* const* d_in, const int* in_sizes, int n_in,
                              void* d_out, int out_size, void* d_ws, size_t ws_size,
                              hipStream_t stream) {
    const float* x   = (const float*)d_in[0];
    const float* emb = (const float*)d_in[1];
    float* norms = (float*)d_ws;   // 1296 floats of scratch

    hipLaunchKernelGGL(vq_enorm, dim3((NUM_CODES + 255) / 256), dim3(256), 0, stream,
                       emb, norms);
    hipLaunchKernelGGL(vq_main, dim3(NUM_Q / BM), dim3(THREADS), 0, stream,
                       x, emb, norms, (float*)d_out);
}

// Round 5
// 284.963 us; speedup vs baseline: 2.5744x; 1.0455x over previous
//
#include <hip/hip_runtime.h>

#define NUM_CODES 1296
#define DDIM 64
#define NUM_Q 131072      // 32*64*64
#define BM 128            // queries per block; 131072 = 1024 * 128 exactly
#define BN 192            // codes per N-tile; 7 tiles cover 1296 (last masked)
#define TM 8              // queries per thread
#define TN 12             // codes per thread
#define KC 16             // k-chunk staged in LDS for embeddings
#define SXLD 128          // sx pitch: av reads conflict-free (4 addrs span 32 banks)
#define SELD 196          // se pitch (192 + 4)
#define NTILE 7
#define THREADS 256       // 16 ty * 16 tx

// Embedding norms ||e||^2, numpy pairwise (8-accumulator) order, contraction off.
__global__ void vq_enorm(const float* __restrict__ emb, float* __restrict__ norms) {
    int k = blockIdx.x * blockDim.x + threadIdx.x;
    if (k >= NUM_CODES) return;
    const float* e = emb + (size_t)k * DDIM;
    {
#pragma clang fp contract(off)
        float r[8];
#pragma unroll
        for (int j = 0; j < 8; ++j) { float t = e[j] * e[j]; r[j] = t; }
#pragma unroll
        for (int i = 1; i < 8; ++i) {
#pragma unroll
            for (int j = 0; j < 8; ++j) { float t = e[i*8+j] * e[i*8+j]; r[j] += t; }
        }
        norms[k] = ((r[0]+r[1])+(r[2]+r[3])) + ((r[4]+r[5])+(r[6]+r[7]));
    }
}

__global__ __launch_bounds__(THREADS, 3) void vq_main(
        const float* __restrict__ x, const float* __restrict__ emb,
        const float* __restrict__ norms, float* __restrict__ out) {
    __shared__ float sx[DDIM * SXLD];   // 32768 B, x tile k-major
    __shared__ float se[KC * SELD];     // 12544 B, e chunk k-major
    __shared__ float sn[BN];            // 768 B
    __shared__ float x1s[BM];           // 512 B   -> total 46592 B, 3 blocks/CU

    const int tid = threadIdx.x;
    const int tx = tid & 15;            // code group
    const int ty = tid >> 4;            // query group (0..15)
    const long qbase = (long)blockIdx.x * BM;

    // ---- stage x tile transposed: sx[d][r] = x[qbase+r][d] ----
    // 2048 float4 / 256 threads = 8 each, coalesced global reads.
    // (writes are 16-way bank-conflicted with SXLD=128 — once per block, negligible)
#pragma unroll
    for (int u = 0; u < 8; ++u) {
        int idx = u * THREADS + tid;
        int r = idx >> 4, j = idx & 15;
        float4 v = *(const float4*)(x + (qbase + r) * DDIM + j * 4);
        sx[(4*j+0)*SXLD + r] = v.x;
        sx[(4*j+1)*SXLD + r] = v.y;
        sx[(4*j+2)*SXLD + r] = v.z;
        sx[(4*j+3)*SXLD + r] = v.w;
    }
    __syncthreads();

    // ---- ||x||^2 per query, numpy pairwise order (element order d=0..63) ----
    if (tid < BM) {
#pragma clang fp contract(off)
        float r8[8];
#pragma unroll
        for (int j = 0; j < 8; ++j) { float v = sx[j*SXLD + tid]; float t = v*v; r8[j] = t; }
#pragma unroll
        for (int i = 1; i < 8; ++i) {
#pragma unroll
            for (int j = 0; j < 8; ++j) { float v = sx[(i*8+j)*SXLD + tid]; float t = v*v; r8[j] += t; }
        }
        x1s[tid] = ((r8[0]+r8[1])+(r8[2]+r8[3])) + ((r8[4]+r8[5])+(r8[6]+r8[7]));
    }
    // x1s written once; first read is after the next __syncthreads().

    float best[TM]; int bestk[TM];
#pragma unroll
    for (int i = 0; i < TM; ++i) { best[i] = __builtin_inff(); bestk[i] = 0; }

    for (int t = 0; t < NTILE; ++t) {
        const int tb = t * BN;
        float acc[TM][TN];
#pragma unroll
        for (int i = 0; i < TM; ++i)
#pragma unroll
            for (int j = 0; j < TN; ++j) acc[i][j] = 0.f;

        for (int kc = 0; kc < DDIM / KC; ++kc) {
            __syncthreads();   // previous chunk fully consumed
            // stage se[k][c] = emb[clamp(tb+c)][kc*KC + k]; 768 float4 / 256 thr
#pragma unroll
            for (int u = 0; u < 3; ++u) {
                int idx = u * THREADS + tid;
                int c = idx >> 2, j = idx & 3;
                int cg = tb + c; if (cg > NUM_CODES - 1) cg = NUM_CODES - 1;
                float4 v = *(const float4*)(emb + (long)cg * DDIM + kc * KC + j * 4);
                se[(4*j+0)*SELD + c] = v.x;
                se[(4*j+1)*SELD + c] = v.y;
                se[(4*j+2)*SELD + c] = v.z;
                se[(4*j+3)*SELD + c] = v.w;
            }
            if (kc == 0) {
                for (int c = tid; c < BN; c += THREADS)
                    sn[c] = (tb + c < NUM_CODES) ? norms[tb + c] : __builtin_inff();
            }
            __syncthreads();

#pragma unroll 2
            for (int k = 0; k < KC; ++k) {
                const float* ap = sx + (kc*KC + k)*SXLD + ty*TM;
                const float* bp = se + k*SELD + tx*TN;
                float av[TM], bv[TN];
#pragma unroll
                for (int p = 0; p < TM/4; ++p) {
                    float4 v = *(const float4*)(ap + 4*p);
                    av[4*p+0]=v.x; av[4*p+1]=v.y; av[4*p+2]=v.z; av[4*p+3]=v.w;
                }
#pragma unroll
                for (int p = 0; p < TN/4; ++p) {
                    float4 v = *(const float4*)(bp + 4*p);
                    bv[4*p+0]=v.x; bv[4*p+1]=v.y; bv[4*p+2]=v.z; bv[4*p+3]=v.w;
                }
#pragma unroll
                for (int i = 0; i < TM; ++i)
#pragma unroll
                    for (int j = 0; j < TN; ++j)
                        acc[i][j] = fmaf(av[i], bv[j], acc[i][j]);  // k ascending: same order as ref
            }
        }

        // ---- argmin update for this tile (codes ascending within thread) ----
#pragma unroll
        for (int i = 0; i < TM; ++i) {
            float x1 = x1s[ty*TM + i];
#pragma unroll
            for (int j = 0; j < TN; ++j) {
                float dist = (x1 + sn[tx*TN + j]) - 2.0f * acc[i][j];
                int kg = tb + tx*TN + j;
                if (dist < best[i]) { best[i] = dist; bestk[i] = kg; }
            }
        }
    }

    // ---- reduce (dist, idx) lexicographically across the 16 tx lanes ----
#pragma unroll
    for (int i = 0; i < TM; ++i) {
        float b = best[i]; int kk = bestk[i];
#pragma unroll
        for (int m = 1; m < 16; m <<= 1) {
            float ob = __shfl_xor(b, m, 64);
            int  ok = __shfl_xor(kk, m, 64);
            if (ob < b || (ob == b && ok < kk)) { b = ob; kk = ok; }
        }
        long q = qbase + ty*TM + i;
        if (tx == 0) out[q] = (float)kk;   // codes as float values
        // 16 lanes gather the 64-float embedding row cooperatively
        *(float4*)(out + (long)NUM_Q + q*DDIM + tx*4) =
            *(const float4*)(emb + (long)kk*DDIM + tx*4);
    }
}

extern "C" void kernel_launch(void* const* d_in, const int* in_sizes, int n_in,
                              void* d_out, int out_size, void* d_ws, size_t ws_size,
                              hipStream_t stream) {
    const float* x   = (const float*)d_in[0];
    const float* emb = (const float*)d_in[1];
    float* norms = (float*)d_ws;   // 1296 floats of scratch

    hipLaunchKernelGGL(vq_enorm, dim3((NUM_CODES + 255) / 256), dim3(256), 0, stream,
                       emb, norms);
    hipLaunchKernelGGL(vq_main, dim3(NUM_Q / BM), dim3(THREADS), 0, stream,
                       x, emb, norms, (float*)d_out);
}